// Round 1
// baseline (233.051 us; speedup 1.0000x reference)
//
#include <hip/hip_runtime.h>
#include <stdint.h>

#define THREADS 1024
#define CAND 2048
#define HBINS 4096

typedef unsigned int u32;
typedef unsigned long long u64;

// order-preserving float->uint map (ascending uint == ascending float)
__device__ __forceinline__ u32 f2s(float f) {
  u32 b = __float_as_uint(f);
  return b ^ ((b & 0x80000000u) ? 0xFFFFFFFFu : 0x80000000u);
}
__device__ __forceinline__ float s2f(u32 s) {
  u32 b = (s & 0x80000000u) ? (s ^ 0x80000000u) : ~s;
  return __uint_as_float(b);
}
__device__ __forceinline__ u32 rotl32(u32 x, int r) { return (x << r) | (x >> (32 - r)); }

// JAX threefry2x32, partitionable counter mode, key = jax.random.key(42) -> (0,42).
// bits(i) = out0 ^ out1 of threefry2x32((0,42), (hi(i)=0, lo(i)=i)).
__device__ __forceinline__ u32 threefry_bits(u32 ctr) {
  const u32 ks0 = 0u, ks1 = 42u, ks2 = 0x1BD11BDAu ^ 0u ^ 42u;
  u32 x0 = ks0;        // counts_hi + ks0
  u32 x1 = ctr + ks1;  // counts_lo + ks1
#define TFR(r) { x0 += x1; x1 = rotl32(x1, (r)); x1 ^= x0; }
  TFR(13) TFR(15) TFR(26) TFR(6)   x0 += ks1; x1 += ks2 + 1u;
  TFR(17) TFR(29) TFR(16) TFR(24)  x0 += ks2; x1 += ks0 + 2u;
  TFR(13) TFR(15) TFR(26) TFR(6)   x0 += ks0; x1 += ks1 + 3u;
  TFR(17) TFR(29) TFR(16) TFR(24)  x0 += ks1; x1 += ks2 + 4u;
  TFR(13) TFR(15) TFR(26) TFR(6)   x0 += ks2; x1 += ks0 + 5u;
#undef TFR
  return x0 ^ x1;
}

__global__ __launch_bounds__(THREADS)
void Sampler_73529840107542_kernel(const float* __restrict__ logits,
                                   const float* __restrict__ temps,
                                   const float* __restrict__ minps,
                                   const float* __restrict__ topps,
                                   const int* __restrict__ topks,
                                   int* __restrict__ out, int V) {
  const int b = blockIdx.x;
  const int tid = threadIdx.x;
  const float* row = logits + (size_t)b * (size_t)V;
  const float t = temps[b];
  const float one_minus_p = 1.0f - topps[b];   // matches ref (1.0 - top_ps) in f32
  const float minp = minps[b];
  int k = topks[b];
  if (k < 1) k = 1;
  if (k > V) k = V;

  // 50KB LDS arena, manually carved (with deliberate stage-disjoint aliasing)
  __shared__ __align__(16) unsigned char arena[51200];
  u32* hist   = (u32*)(arena);              // [0,16384)   histogram / suffix scan ping
  u32* scanB  = (u32*)(arena + 16384);      // suffix scan pong (aliases cand)
  u64* cand   = (u64*)(arena + 16384);      // [16384,32768) candidate (val,idx) keys
  float* bufA = (float*)(arena + 32768);    // [32768,40960) e / p values
  float* bufB = (float*)(arena + 40960);    // [40960,49152) cumsum / reduce scratch
  unsigned char* keepf = arena + 49152;     // [49152,51200)
  u64* red64  = (u64*)(arena + 32768);      // aliases bufA (argmax stage only)
  float* redA = (float*)(arena + 32768);    // aliases bufA (Z2 stage only)
  float* redB = (float*)(arena + 40960);    // aliases bufB (Z1 stage only)

  __shared__ int sh_cnt, sh_h1, sh_cs;
  __shared__ u32 sh_Ts;
  __shared__ float sh_m, sh_Z1, sh_Z2;

  // ---- phase 1: coarse histogram over top-12 bits of sortable key ----
  for (int i = tid; i < HBINS; i += THREADS) hist[i] = 0u;
  if (tid == 0) sh_cnt = 0;
  __syncthreads();
  for (int v = tid; v < V; v += THREADS) {
    float x = row[v] / t;                  // exact IEEE division, same as ref
    atomicAdd(&hist[f2s(x) >> 20], 1u);
  }
  __syncthreads();

  // ---- suffix-inclusive scan over bins; pick bin holding the k-th largest ----
  {
    u32* sA = hist;
    u32* sB = scanB;
    for (int off = 1; off < HBINS; off <<= 1) {   // 12 rounds (even -> ends in hist)
      for (int i = tid; i < HBINS; i += THREADS) {
        u32 v2 = sA[i];
        if (i + off < HBINS) v2 += sA[i + off];
        sB[i] = v2;
      }
      u32* tmp = sA; sA = sB; sB = tmp;
      __syncthreads();
    }
    const u32 ku = (u32)k;
    for (int i = tid; i < HBINS; i += THREADS) {
      u32 inc = sA[i];
      u32 nxt = (i + 1 < HBINS) ? sA[i + 1] : 0u;
      if (inc >= ku && nxt < ku) {          // unique i (suffix sums non-increasing)
        sh_h1 = i;
        sh_cs = (int)(inc < (u32)CAND ? inc : (u32)CAND);
      }
    }
    __syncthreads();
  }

  // ---- phase 2: collect candidates (everything in/above the boundary bin) ----
  const u32 thr = ((u32)sh_h1) << 20;
  for (int v = tid; v < V; v += THREADS) {
    float x = row[v] / t;
    u32 s = f2s(x);
    if (s >= thr) {
      int pos = atomicAdd(&sh_cnt, 1);
      if (pos < CAND) cand[pos] = ((u64)s << 32) | (u32)v;
    }
  }
  __syncthreads();
  const int cs = sh_cs;
  for (int c = tid; c < CAND; c += THREADS)
    if (c >= cs) cand[c] = 0xFFFFFFFFFFFFFFFFull;   // pad sentinels sort to top
  __syncthreads();

  // ---- bitonic sort: (value, idx) ascending == JAX stable ascending argsort ----
  for (int size = 2; size <= CAND; size <<= 1) {
    for (int stride = size >> 1; stride > 0; stride >>= 1) {
      for (int i = tid; i < CAND; i += THREADS) {
        int j = i ^ stride;
        if (j > i) {
          u64 a = cand[i], bb = cand[j];
          bool asc = ((i & size) == 0);
          if ((a > bb) == asc) { cand[i] = bb; cand[j] = a; }
        }
      }
      __syncthreads();
    }
  }

  if (tid == 0) {
    int ti = cs - k; if (ti < 0) ti = 0;
    sh_Ts = (u32)(cand[ti] >> 32);             // k-th largest value (exact)
    sh_m  = s2f((u32)(cand[cs - 1] >> 32));    // row max
  }
  __syncthreads();
  const u32 Ts = sh_Ts;
  const float m = sh_m;

  // ---- e = exp(x - m); 0 for top-k-masked / pad ----
  for (int c = tid; c < CAND; c += THREADS) {
    float e = 0.0f;
    if (c < cs) {
      u32 s = (u32)(cand[c] >> 32);
      if (s >= Ts) e = expf(s2f(s) - m);       // strict '< T' masked, ties at T kept
    }
    bufA[c] = e;
  }
  __syncthreads();

  // ---- Z1 (softmax denom after top-k), deterministic tree reduce ----
  {
    float local = bufA[tid] + bufA[tid + THREADS];
    redB[tid] = local;
    __syncthreads();
    for (int s = THREADS >> 1; s > 0; s >>= 1) {
      if (tid < s) redB[tid] += redB[tid + s];
      __syncthreads();
    }
    if (tid == 0) sh_Z1 = redB[0];
    __syncthreads();
  }

  // ---- p = e / Z1 (per-element division like ref), sequential cumsum ----
  const float Z1 = sh_Z1;
  for (int c = tid; c < CAND; c += THREADS) bufA[c] = bufA[c] / Z1;
  __syncthreads();
  if (tid == 0) {
    float acc = 0.0f;                      // masked positions add exact 0.0f ->
    for (int c = 0; c < cs; ++c) {         // identical to full-row sequential cumsum
      acc += bufA[c];
      bufB[c] = acc;
    }
  }
  __syncthreads();

  // ---- top-p keep flags: drop iff cumsum <= 1-p, never drop last sorted pos ----
  for (int c = tid; c < CAND; c += THREADS) {
    unsigned char kf = 0;
    if (c < cs) {
      u32 s = (u32)(cand[c] >> 32);
      if (s >= Ts && (c == cs - 1 || bufB[c] > one_minus_p)) kf = 1;
    }
    keepf[c] = kf;
  }
  __syncthreads();

  // ---- Z2 (softmax denom after top-p), deterministic tree reduce ----
  {
    float local = 0.0f;
    for (int c = tid; c < CAND; c += THREADS) {
      if (keepf[c]) {
        u32 s = (u32)(cand[c] >> 32);
        local += expf(s2f(s) - m);
      }
    }
    redA[tid] = local;
    __syncthreads();
    for (int s = THREADS >> 1; s > 0; s >>= 1) {
      if (tid < s) redA[tid] += redA[tid + s];
      __syncthreads();
    }
    if (tid == 0) sh_Z2 = redA[0];
    __syncthreads();
  }

  // ---- min_p: remove iff (e/Z2) < min_p * (1/Z2)  (top prob == fl(1/Z2)) ----
  {
    const float Z2 = sh_Z2;
    const float rhs = minp * (1.0f / Z2);
    for (int c = tid; c < CAND; c += THREADS) {
      if (keepf[c]) {
        u32 s = (u32)(cand[c] >> 32);
        float p2 = expf(s2f(s) - m) / Z2;
        if (p2 < rhs) keepf[c] = 0;
      }
    }
  }
  __syncthreads();

  // ---- gumbel-max over kept candidates (JAX categorical), first-index ties ----
  {
    const float TINY = 1.17549435082228750797e-38f;  // 2^-126, np.finfo(f32).tiny
    u64 best = 0ull;
    for (int c = tid; c < cs; c += THREADS) {
      if (!keepf[c]) continue;
      u32 s = (u32)(cand[c] >> 32);
      u32 idx = (u32)(cand[c] & 0xFFFFFFFFull);
      float x = s2f(s);
      u32 bits = threefry_bits((u32)b * (u32)V + idx);
      float f = __uint_as_float((bits >> 9) | 0x3f800000u) - 1.0f;  // [0,1)
      float u = fmaxf(TINY, f * 1.0f + TINY);                       // jax _uniform
      float g = -logf(-logf(u));                                    // gumbel
      float sc = g + x;
      // max score, tie -> smaller original index (jnp.argmax first occurrence)
      u64 key = ((u64)f2s(sc) << 32) | (u64)(0xFFFFFFFFu - idx);
      if (key > best) best = key;
    }
    red64[tid] = best;
    __syncthreads();
    for (int s = THREADS >> 1; s > 0; s >>= 1) {
      if (tid < s) { u64 o = red64[tid + s]; if (o > red64[tid]) red64[tid] = o; }
      __syncthreads();
    }
    if (tid == 0) out[b] = (int)(0xFFFFFFFFu - (u32)(red64[0] & 0xFFFFFFFFull));
  }
}

extern "C" void kernel_launch(void* const* d_in, const int* in_sizes, int n_in,
                              void* d_out, int out_size, void* d_ws, size_t ws_size,
                              hipStream_t stream) {
  const float* logits = (const float*)d_in[0];
  const float* temps  = (const float*)d_in[1];
  const float* minps  = (const float*)d_in[2];
  const float* topps  = (const float*)d_in[3];
  const int*   topks  = (const int*)d_in[4];
  const int B = in_sizes[1];
  const int V = in_sizes[0] / B;
  (void)n_in; (void)out_size; (void)d_ws; (void)ws_size;
  Sampler_73529840107542_kernel<<<dim3(B), dim3(THREADS), 0, stream>>>(
      logits, temps, minps, topps, topks, (int*)d_out, V);
}

// Round 2
// 217.231 us; speedup vs baseline: 1.0728x; 1.0728x over previous
//
#include <hip/hip_runtime.h>
#include <stdint.h>

#define THREADS 1024
#define CAND 2048
#define HBINS 4096
#define NSLICES 4
#define HTHREADS 256

typedef unsigned int u32;
typedef unsigned long long u64;

// order-preserving float->uint map (ascending uint == ascending float)
__device__ __forceinline__ u32 f2s(float f) {
  u32 b = __float_as_uint(f);
  return b ^ ((b & 0x80000000u) ? 0xFFFFFFFFu : 0x80000000u);
}
__device__ __forceinline__ float s2f(u32 s) {
  u32 b = (s & 0x80000000u) ? (s ^ 0x80000000u) : ~s;
  return __uint_as_float(b);
}
__device__ __forceinline__ u32 rotl32(u32 x, int r) { return (x << r) | (x >> (32 - r)); }

// JAX threefry2x32, partitionable counter mode, key = jax.random.key(42) -> (0,42).
__device__ __forceinline__ u32 threefry_bits(u32 ctr) {
  const u32 ks0 = 0u, ks1 = 42u, ks2 = 0x1BD11BDAu ^ 0u ^ 42u;
  u32 x0 = ks0;
  u32 x1 = ctr + ks1;
#define TFR(r) { x0 += x1; x1 = rotl32(x1, (r)); x1 ^= x0; }
  TFR(13) TFR(15) TFR(26) TFR(6)   x0 += ks1; x1 += ks2 + 1u;
  TFR(17) TFR(29) TFR(16) TFR(24)  x0 += ks2; x1 += ks0 + 2u;
  TFR(13) TFR(15) TFR(26) TFR(6)   x0 += ks0; x1 += ks1 + 3u;
  TFR(17) TFR(29) TFR(16) TFR(24)  x0 += ks1; x1 += ks2 + 4u;
  TFR(13) TFR(15) TFR(26) TFR(6)   x0 += ks2; x1 += ks0 + 5u;
#undef TFR
  return x0 ^ x1;
}

// ---------------- zero the global histogram (graph-capture-safe) --------------
__global__ __launch_bounds__(1024)
void zero_kernel(u32* __restrict__ p, int n) {
  int i = blockIdx.x * 1024 + threadIdx.x;
  if (i < n) p[i] = 0u;
}

// ---------------- per-slice raw-logit histogram (no division!) ----------------
__global__ __launch_bounds__(HTHREADS)
void hist_kernel(const float* __restrict__ logits, u32* __restrict__ ghist,
                 int V, int slice_len) {
  const int row = blockIdx.x / NSLICES;
  const int sl  = blockIdx.x % NSLICES;
  const int tid = threadIdx.x;
  __shared__ u32 h[HBINS];
  for (int i = tid; i < HBINS; i += HTHREADS) h[i] = 0u;
  __syncthreads();
  int rem = V - sl * slice_len;
  if (rem > slice_len) rem = slice_len;
  if (rem < 0) rem = 0;
  const float* src = logits + (size_t)row * (size_t)V + (size_t)sl * slice_len;
  const int n4 = rem >> 2;
  const float4* p4 = (const float4*)src;  // slice_len is 16B-aligned multiple of 4
  for (int i = tid; i < n4; i += HTHREADS) {
    float4 w = p4[i];
    atomicAdd(&h[f2s(w.x) >> 20], 1u);
    atomicAdd(&h[f2s(w.y) >> 20], 1u);
    atomicAdd(&h[f2s(w.z) >> 20], 1u);
    atomicAdd(&h[f2s(w.w) >> 20], 1u);
  }
  for (int i = (n4 << 2) + tid; i < rem; i += HTHREADS)
    atomicAdd(&h[f2s(src[i]) >> 20], 1u);
  __syncthreads();
  u32* gh = ghist + (size_t)row * HBINS;
  for (int i = tid; i < HBINS; i += HTHREADS) {
    u32 c = h[i];
    if (c) atomicAdd(&gh[i], c);   // sparse: ~300 active bins/block
  }
}

// ---------------- per-row: threshold find + collect + sort + sample ----------
__global__ __launch_bounds__(THREADS)
void Sampler_73529840107542_kernel(const float* __restrict__ logits,
                                   const float* __restrict__ temps,
                                   const float* __restrict__ minps,
                                   const float* __restrict__ topps,
                                   const int* __restrict__ topks,
                                   const u32* __restrict__ ghist,
                                   int* __restrict__ out, int V) {
  const int b = blockIdx.x;
  const int tid = threadIdx.x;
  const float* row = logits + (size_t)b * (size_t)V;
  const float t = temps[b];
  const float one_minus_p = 1.0f - topps[b];
  const float minp = minps[b];
  int k = topks[b];
  if (k < 1) k = 1;
  if (k > V) k = V;

  __shared__ __align__(16) unsigned char arena[51200];
  u32* hist   = (u32*)(arena);              // [0,16384)    histogram row
  u64* cand   = (u64*)(arena + 16384);      // [16384,32768) candidate (x,idx) keys
  float* bufA = (float*)(arena + 32768);    // [32768,40960) e / p values
  float* bufB = (float*)(arena + 40960);    // [40960,49152) cumsum scratch
  unsigned char* keepf = arena + 49152;     // [49152,51200)
  u32* part   = (u32*)(arena + 32768);      // aliases bufA (threshold stage only)
  u64* red64  = (u64*)(arena + 32768);      // aliases bufA (argmax stage only)
  float* redA = (float*)(arena + 32768);    // aliases bufA (Z2 stage only)
  float* redB = (float*)(arena + 40960);    // aliases bufB (Z1 stage only)

  __shared__ u32 chunk[64];
  __shared__ int sh_cnt, sh_h1, sh_cs, sh_lb;
  __shared__ u32 sh_Ts;
  __shared__ float sh_m, sh_Z1, sh_Z2;

  // ---- load this row's histogram ----
  const u32* gh = ghist + (size_t)b * HBINS;
  for (int i = tid; i < HBINS; i += THREADS) hist[i] = gh[i];
  __syncthreads();

  // ---- hierarchical suffix-find of the k-th-largest's bin ----
  part[tid] = hist[tid * 4] + hist[tid * 4 + 1] + hist[tid * 4 + 2] + hist[tid * 4 + 3];
  __syncthreads();
  if (tid < 64) {
    u32 s = 0;
    for (int j = 0; j < 16; ++j) s += part[tid * 16 + j];
    chunk[tid] = s;
  }
  __syncthreads();
  if (tid == 0) {
    const u32 ku = (u32)k;
    u32 acc = 0;
    int cstar = 0;
    for (int c = 63; c >= 0; --c) {
      if (acc + chunk[c] >= ku) { cstar = c; break; }
      acc += chunk[c];
    }
    u32 accA = acc;
    int bstar = cstar * 64;
    for (int bq = cstar * 64 + 63; bq >= cstar * 64; --bq) {
      accA += hist[bq];
      if (accA >= ku) { bstar = bq; break; }
    }
    sh_h1 = bstar;
    sh_cs = (int)(accA < (u32)CAND ? accA : (u32)CAND);
    sh_cnt = 0;
  }
  __syncthreads();

  // ---- collect pass: raw threshold, divide only the hits ----
  const u32 thr = ((u32)sh_h1) << 20;
  {
    const int n4 = V >> 2;
    const float4* p4 = (const float4*)row;
    for (int i = tid; i < n4; i += THREADS) {
      float4 w = p4[i];
      u32 sx = f2s(w.x), sy = f2s(w.y), sz = f2s(w.z), sw = f2s(w.w);
      if (sx >= thr) { int pos = atomicAdd(&sh_cnt, 1); if (pos < CAND) { float x = w.x / t; cand[pos] = ((u64)f2s(x) << 32) | (u32)(4 * i + 0); } }
      if (sy >= thr) { int pos = atomicAdd(&sh_cnt, 1); if (pos < CAND) { float x = w.y / t; cand[pos] = ((u64)f2s(x) << 32) | (u32)(4 * i + 1); } }
      if (sz >= thr) { int pos = atomicAdd(&sh_cnt, 1); if (pos < CAND) { float x = w.z / t; cand[pos] = ((u64)f2s(x) << 32) | (u32)(4 * i + 2); } }
      if (sw >= thr) { int pos = atomicAdd(&sh_cnt, 1); if (pos < CAND) { float x = w.w / t; cand[pos] = ((u64)f2s(x) << 32) | (u32)(4 * i + 3); } }
    }
    for (int v = (n4 << 2) + tid; v < V; v += THREADS) {
      float l = row[v];
      u32 s = f2s(l);
      if (s >= thr) { int pos = atomicAdd(&sh_cnt, 1); if (pos < CAND) { float x = l / t; cand[pos] = ((u64)f2s(x) << 32) | (u32)v; } }
    }
  }
  __syncthreads();
  const int cs = sh_cs;
  for (int c = tid; c < CAND; c += THREADS)
    if (c >= cs) cand[c] = 0xFFFFFFFFFFFFFFFFull;
  __syncthreads();

  // ---- bitonic sort: (x, idx) ascending == JAX stable ascending argsort ----
  for (int size = 2; size <= CAND; size <<= 1) {
    for (int stride = size >> 1; stride > 0; stride >>= 1) {
      for (int i = tid; i < CAND; i += THREADS) {
        int j = i ^ stride;
        if (j > i) {
          u64 a = cand[i], bb = cand[j];
          bool asc = ((i & size) == 0);
          if ((a > bb) == asc) { cand[i] = bb; cand[j] = a; }
        }
      }
      __syncthreads();
    }
  }

  if (tid == 0) {
    int ti = cs - k; if (ti < 0) ti = 0;
    sh_Ts = (u32)(cand[ti] >> 32);             // k-th largest x (exact)
    sh_m  = s2f((u32)(cand[cs - 1] >> 32));    // row max
  }
  __syncthreads();
  const u32 Ts = sh_Ts;
  const float m = sh_m;

  // ---- first survivor slot (values >= Ts are a contiguous suffix) ----
  for (int c = tid; c < CAND; c += THREADS) {
    if (c < cs) {
      u32 s = (u32)(cand[c] >> 32);
      if (s >= Ts && (c == 0 || (u32)(cand[c - 1] >> 32) < Ts)) sh_lb = c;
    }
  }
  __syncthreads();
  const int lb = sh_lb;

  // ---- e = exp(x - m); 0 for top-k-masked / pad ----
  for (int c = tid; c < CAND; c += THREADS) {
    float e = 0.0f;
    if (c < cs) {
      u32 s = (u32)(cand[c] >> 32);
      if (s >= Ts) e = expf(s2f(s) - m);
    }
    bufA[c] = e;
  }
  __syncthreads();

  // ---- Z1 tree reduce ----
  {
    float local = bufA[tid] + bufA[tid + THREADS];
    redB[tid] = local;
    __syncthreads();
    for (int s = THREADS >> 1; s > 0; s >>= 1) {
      if (tid < s) redB[tid] += redB[tid + s];
      __syncthreads();
    }
    if (tid == 0) sh_Z1 = redB[0];
    __syncthreads();
  }

  // ---- p = e/Z1, sequential cumsum over survivors (zeros are exact identity) --
  const float Z1 = sh_Z1;
  for (int c = tid; c < CAND; c += THREADS) bufA[c] = bufA[c] / Z1;
  __syncthreads();
  if (tid == 0) {
    float acc = 0.0f;
    for (int c = lb; c < cs; ++c) {
      acc += bufA[c];
      bufB[c] = acc;
    }
  }
  __syncthreads();

  // ---- top-p keep flags ----
  for (int c = tid; c < CAND; c += THREADS) {
    unsigned char kf = 0;
    if (c < cs) {
      u32 s = (u32)(cand[c] >> 32);
      if (s >= Ts && (c == cs - 1 || bufB[c] > one_minus_p)) kf = 1;
    }
    keepf[c] = kf;
  }
  __syncthreads();

  // ---- Z2 tree reduce ----
  {
    float local = 0.0f;
    for (int c = tid; c < CAND; c += THREADS) {
      if (keepf[c]) {
        u32 s = (u32)(cand[c] >> 32);
        local += expf(s2f(s) - m);
      }
    }
    redA[tid] = local;
    __syncthreads();
    for (int s = THREADS >> 1; s > 0; s >>= 1) {
      if (tid < s) redA[tid] += redA[tid + s];
      __syncthreads();
    }
    if (tid == 0) sh_Z2 = redA[0];
    __syncthreads();
  }

  // ---- min_p ----
  {
    const float Z2 = sh_Z2;
    const float rhs = minp * (1.0f / Z2);
    for (int c = tid; c < CAND; c += THREADS) {
      if (keepf[c]) {
        u32 s = (u32)(cand[c] >> 32);
        float p2 = expf(s2f(s) - m) / Z2;
        if (p2 < rhs) keepf[c] = 0;
      }
    }
  }
  __syncthreads();

  // ---- gumbel-max (JAX categorical), first-index tie-break ----
  {
    const float TINY = 1.17549435082228750797e-38f;
    u64 best = 0ull;
    for (int c = lb + tid; c < cs; c += THREADS) {
      if (!keepf[c]) continue;
      u32 s = (u32)(cand[c] >> 32);
      u32 idx = (u32)(cand[c] & 0xFFFFFFFFull);
      float x = s2f(s);
      u32 bits = threefry_bits((u32)b * (u32)V + idx);
      float f = __uint_as_float((bits >> 9) | 0x3f800000u) - 1.0f;
      float u = fmaxf(TINY, f * 1.0f + TINY);
      float g = -logf(-logf(u));
      float sc = g + x;
      u64 key = ((u64)f2s(sc) << 32) | (u64)(0xFFFFFFFFu - idx);
      if (key > best) best = key;
    }
    red64[tid] = best;
    __syncthreads();
    for (int s = THREADS >> 1; s > 0; s >>= 1) {
      if (tid < s) { u64 o = red64[tid + s]; if (o > red64[tid]) red64[tid] = o; }
      __syncthreads();
    }
    if (tid == 0) out[b] = (int)(0xFFFFFFFFu - (u32)(red64[0] & 0xFFFFFFFFull));
  }
}

extern "C" void kernel_launch(void* const* d_in, const int* in_sizes, int n_in,
                              void* d_out, int out_size, void* d_ws, size_t ws_size,
                              hipStream_t stream) {
  const float* logits = (const float*)d_in[0];
  const float* temps  = (const float*)d_in[1];
  const float* minps  = (const float*)d_in[2];
  const float* topps  = (const float*)d_in[3];
  const int*   topks  = (const int*)d_in[4];
  const int B = in_sizes[1];
  const int V = in_sizes[0] / B;
  (void)n_in; (void)out_size; (void)ws_size;

  u32* ghist = (u32*)d_ws;                       // B*HBINS u32 = 2 MB
  const int nh = B * HBINS;
  const int slice_len = (((V + NSLICES - 1) / NSLICES) + 3) & ~3;  // 16B-aligned slices

  zero_kernel<<<dim3((nh + 1023) / 1024), dim3(1024), 0, stream>>>(ghist, nh);
  hist_kernel<<<dim3(B * NSLICES), dim3(HTHREADS), 0, stream>>>(logits, ghist, V, slice_len);
  Sampler_73529840107542_kernel<<<dim3(B), dim3(THREADS), 0, stream>>>(
      logits, temps, minps, topps, topks, ghist, (int*)d_out, V);
}

// Round 3
// 202.116 us; speedup vs baseline: 1.1531x; 1.0748x over previous
//
#include <hip/hip_runtime.h>
#include <stdint.h>

#define HBINS 4096
#define CAND 2048
#define NSLICES 16
#define HTHREADS 256
#define CTHREADS 256
#define STHREADS 1024

typedef unsigned int u32;
typedef unsigned long long u64;

// order-preserving float->uint map (ascending uint == ascending float)
__device__ __forceinline__ u32 f2s(float f) {
  u32 b = __float_as_uint(f);
  return b ^ ((b & 0x80000000u) ? 0xFFFFFFFFu : 0x80000000u);
}
__device__ __forceinline__ float s2f(u32 s) {
  u32 b = (s & 0x80000000u) ? (s ^ 0x80000000u) : ~s;
  return __uint_as_float(b);
}
__device__ __forceinline__ u32 rotl32(u32 x, int r) { return (x << r) | (x >> (32 - r)); }

// JAX threefry2x32, partitionable counter mode, key = jax.random.key(42) -> (0,42).
__device__ __forceinline__ u32 threefry_bits(u32 ctr) {
  const u32 ks0 = 0u, ks1 = 42u, ks2 = 0x1BD11BDAu ^ 0u ^ 42u;
  u32 x0 = ks0;
  u32 x1 = ctr + ks1;
#define TFR(r) { x0 += x1; x1 = rotl32(x1, (r)); x1 ^= x0; }
  TFR(13) TFR(15) TFR(26) TFR(6)   x0 += ks1; x1 += ks2 + 1u;
  TFR(17) TFR(29) TFR(16) TFR(24)  x0 += ks2; x1 += ks0 + 2u;
  TFR(13) TFR(15) TFR(26) TFR(6)   x0 += ks0; x1 += ks1 + 3u;
  TFR(17) TFR(29) TFR(16) TFR(24)  x0 += ks1; x1 += ks2 + 4u;
  TFR(13) TFR(15) TFR(26) TFR(6)   x0 += ks2; x1 += ks0 + 5u;
#undef TFR
  return x0 ^ x1;
}

// ---------------- zero scratch (graph-capture-safe) ---------------------------
__global__ __launch_bounds__(1024)
void zero_kernel(u32* __restrict__ p, int n) {
  int i = blockIdx.x * 1024 + threadIdx.x;
  if (i < n) p[i] = 0u;
}

// ---------------- per-slice raw-logit histogram (full machine) ----------------
__global__ __launch_bounds__(HTHREADS)
void hist_kernel(const float* __restrict__ logits, u32* __restrict__ ghist,
                 int V, int slice_len) {
  const int row = blockIdx.x / NSLICES;
  const int sl  = blockIdx.x % NSLICES;
  const int tid = threadIdx.x;
  __shared__ u32 h[HBINS];
  for (int i = tid; i < HBINS; i += HTHREADS) h[i] = 0u;
  __syncthreads();
  int rem = V - sl * slice_len;
  if (rem > slice_len) rem = slice_len;
  if (rem < 0) rem = 0;
  const float* src = logits + (size_t)row * (size_t)V + (size_t)sl * slice_len;
  const int n4 = rem >> 2;
  const float4* p4 = (const float4*)src;  // slice_len multiple of 4 -> 16B aligned
  for (int i = tid; i < n4; i += HTHREADS) {
    float4 w = p4[i];
    atomicAdd(&h[f2s(w.x) >> 20], 1u);
    atomicAdd(&h[f2s(w.y) >> 20], 1u);
    atomicAdd(&h[f2s(w.z) >> 20], 1u);
    atomicAdd(&h[f2s(w.w) >> 20], 1u);
  }
  for (int i = (n4 << 2) + tid; i < rem; i += HTHREADS)
    atomicAdd(&h[f2s(src[i]) >> 20], 1u);
  __syncthreads();
  u32* gh = ghist + (size_t)row * HBINS;
  for (int i = tid; i < HBINS; i += HTHREADS) {
    u32 c = h[i];
    if (c) atomicAdd(&gh[i], c);   // sparse merge
  }
}

// ---------------- per-slice collect (full machine) ----------------------------
__global__ __launch_bounds__(CTHREADS)
void collect_kernel(const float* __restrict__ logits,
                    const float* __restrict__ temps,
                    const int* __restrict__ topks,
                    const u32* __restrict__ ghist,
                    u32* __restrict__ gcount, u32* __restrict__ gcs,
                    u64* __restrict__ gcand, int V, int slice_len) {
  const int row = blockIdx.x / NSLICES;
  const int sl  = blockIdx.x % NSLICES;
  const int tid = threadIdx.x;

  __shared__ u32 hist[HBINS];     // 16 KB
  __shared__ u64 stage[CAND];     // 16 KB
  __shared__ u32 part[CTHREADS];
  __shared__ u32 chunk[64];
  __shared__ int sh_cnt, sh_thr, sh_base;

  const u32* gh = ghist + (size_t)row * HBINS;
  for (int i = tid; i < HBINS; i += CTHREADS) hist[i] = gh[i];
  __syncthreads();

  // hierarchical suffix-find of the bin holding the k-th largest (redundant/block)
  {
    u32 s = 0;
    for (int j = 0; j < 16; ++j) s += hist[tid * 16 + j];
    part[tid] = s;
  }
  __syncthreads();
  if (tid < 64) {
    u32 s = part[tid * 4] + part[tid * 4 + 1] + part[tid * 4 + 2] + part[tid * 4 + 3];
    chunk[tid] = s;
  }
  __syncthreads();
  if (tid == 0) {
    int k = topks[row];
    if (k < 1) k = 1;
    if (k > V) k = V;
    const u32 ku = (u32)k;
    u32 acc = 0;
    int cstar = 0;
    for (int c = 63; c >= 0; --c) {
      if (acc + chunk[c] >= ku) { cstar = c; break; }
      acc += chunk[c];
    }
    int pstar = cstar * 4;
    for (int p = cstar * 4 + 3; p >= cstar * 4; --p) {
      if (acc + part[p] >= ku) { pstar = p; break; }
      acc += part[p];
    }
    int bstar = pstar * 16;
    for (int bq = pstar * 16 + 15; bq >= pstar * 16; --bq) {
      acc += hist[bq];
      if (acc >= ku) { bstar = bq; break; }
    }
    sh_thr = bstar;
    sh_cnt = 0;
    if (sl == 0) gcs[row] = (acc < (u32)CAND ? acc : (u32)CAND);
  }
  __syncthreads();

  const u32 thr = ((u32)sh_thr) << 20;
  const float t = temps[row];
  int rem = V - sl * slice_len;
  if (rem > slice_len) rem = slice_len;
  if (rem < 0) rem = 0;
  const float* src = logits + (size_t)row * (size_t)V + (size_t)sl * slice_len;
  const u32 ibase = (u32)(sl * slice_len);
  const int n4 = rem >> 2;
  const float4* p4 = (const float4*)src;
  for (int i = tid; i < n4; i += CTHREADS) {
    float4 w = p4[i];
    u32 sx = f2s(w.x), sy = f2s(w.y), sz = f2s(w.z), sw = f2s(w.w);
    if (sx >= thr) { int pos = atomicAdd(&sh_cnt, 1); if (pos < CAND) stage[pos] = ((u64)f2s(w.x / t) << 32) | (ibase + 4u * i + 0u); }
    if (sy >= thr) { int pos = atomicAdd(&sh_cnt, 1); if (pos < CAND) stage[pos] = ((u64)f2s(w.y / t) << 32) | (ibase + 4u * i + 1u); }
    if (sz >= thr) { int pos = atomicAdd(&sh_cnt, 1); if (pos < CAND) stage[pos] = ((u64)f2s(w.z / t) << 32) | (ibase + 4u * i + 2u); }
    if (sw >= thr) { int pos = atomicAdd(&sh_cnt, 1); if (pos < CAND) stage[pos] = ((u64)f2s(w.w / t) << 32) | (ibase + 4u * i + 3u); }
  }
  for (int i = (n4 << 2) + tid; i < rem; i += CTHREADS) {
    float l = src[i];
    if (f2s(l) >= thr) { int pos = atomicAdd(&sh_cnt, 1); if (pos < CAND) stage[pos] = ((u64)f2s(l / t) << 32) | (ibase + (u32)i); }
  }
  __syncthreads();
  int n = sh_cnt;
  if (n > CAND) n = CAND;
  if (tid == 0) sh_base = (int)atomicAdd(&gcount[row], (u32)n);
  __syncthreads();
  const int base = sh_base;
  u64* gc = gcand + (size_t)row * CAND;
  for (int i = tid; i < n; i += CTHREADS) {
    int dst = base + i;
    if (dst < CAND) gc[dst] = stage[i];
  }
}

// ---------------- per-row: sort + softmax chain + gumbel sample ---------------
__global__ __launch_bounds__(STHREADS)
void Sampler_73529840107542_kernel(const float* __restrict__ minps,
                                   const float* __restrict__ topps,
                                   const int* __restrict__ topks,
                                   const u32* __restrict__ gcs,
                                   const u64* __restrict__ gcand,
                                   int* __restrict__ out, int V) {
  const int b = blockIdx.x;
  const int tid = threadIdx.x;
  const float one_minus_p = 1.0f - topps[b];
  const float minp = minps[b];
  int k = topks[b];
  if (k < 1) k = 1;
  if (k > V) k = V;

  __shared__ __align__(16) unsigned char arena[34816];
  u64* cand   = (u64*)(arena);              // [0,16384)
  float* bufA = (float*)(arena + 16384);    // [16384,24576) e / p
  float* bufB = (float*)(arena + 24576);    // [24576,32768) cumsum
  unsigned char* keepf = arena + 32768;     // [32768,34816)
  u64* red64  = (u64*)(arena + 16384);      // aliases bufA (argmax stage)
  float* redA = (float*)(arena + 16384);    // aliases bufA (Z2 stage)
  float* redB = (float*)(arena + 24576);    // aliases bufB (Z1 stage)

  __shared__ int sh_lb;
  __shared__ u32 sh_Ts;
  __shared__ float sh_m, sh_Z1, sh_Z2;

  const int cs = (int)gcs[b];
  int SN = 64;
  while (SN < cs) SN <<= 1;

  const u64* gc = gcand + (size_t)b * CAND;
  for (int c = tid; c < SN; c += STHREADS)
    cand[c] = (c < cs) ? gc[c] : 0xFFFFFFFFFFFFFFFFull;
  __syncthreads();

  // bitonic sort of SN entries: (x, idx) ascending == JAX stable ascending argsort
  for (int size = 2; size <= SN; size <<= 1) {
    for (int stride = size >> 1; stride > 0; stride >>= 1) {
      for (int i = tid; i < SN; i += STHREADS) {
        int j = i ^ stride;
        if (j > i) {
          u64 a = cand[i], bb = cand[j];
          bool asc = ((i & size) == 0);
          if ((a > bb) == asc) { cand[i] = bb; cand[j] = a; }
        }
      }
      __syncthreads();
    }
  }

  if (tid == 0) {
    int ti = cs - k; if (ti < 0) ti = 0;
    sh_Ts = (u32)(cand[ti] >> 32);             // k-th largest x (exact)
    sh_m  = s2f((u32)(cand[cs - 1] >> 32));    // row max
  }
  __syncthreads();
  const u32 Ts = sh_Ts;
  const float m = sh_m;

  // first survivor slot (values >= Ts form a contiguous suffix of [0,cs))
  for (int c = tid; c < cs; c += STHREADS) {
    u32 s = (u32)(cand[c] >> 32);
    if (s >= Ts && (c == 0 || (u32)(cand[c - 1] >> 32) < Ts)) sh_lb = c;
  }
  __syncthreads();
  const int lb = sh_lb;

  // e = exp(x - m); exact 0 for masked / pad
  for (int c = tid; c < CAND; c += STHREADS) {
    float e = 0.0f;
    if (c < cs) {
      u32 s = (u32)(cand[c] >> 32);
      if (s >= Ts) e = expf(s2f(s) - m);
    }
    bufA[c] = e;
  }
  __syncthreads();

  // Z1 tree reduce
  {
    float local = bufA[tid] + bufA[tid + STHREADS];
    redB[tid] = local;
    __syncthreads();
    for (int s = STHREADS >> 1; s > 0; s >>= 1) {
      if (tid < s) redB[tid] += redB[tid + s];
      __syncthreads();
    }
    if (tid == 0) sh_Z1 = redB[0];
    __syncthreads();
  }

  // p = e/Z1, sequential cumsum over survivors (exact-zero adds are identity)
  const float Z1 = sh_Z1;
  for (int c = tid; c < CAND; c += STHREADS) bufA[c] = bufA[c] / Z1;
  __syncthreads();
  if (tid == 0) {
    float acc = 0.0f;
    for (int c = lb; c < cs; ++c) {
      acc += bufA[c];
      bufB[c] = acc;
    }
  }
  __syncthreads();

  // top-p keep flags: drop iff cumsum <= 1-p, never drop last sorted pos
  for (int c = tid; c < CAND; c += STHREADS) {
    unsigned char kf = 0;
    if (c < cs) {
      u32 s = (u32)(cand[c] >> 32);
      if (s >= Ts && (c == cs - 1 || bufB[c] > one_minus_p)) kf = 1;
    }
    keepf[c] = kf;
  }
  __syncthreads();

  // Z2 tree reduce
  {
    float local = 0.0f;
    for (int c = tid; c < CAND; c += STHREADS) {
      if (keepf[c]) {
        u32 s = (u32)(cand[c] >> 32);
        local += expf(s2f(s) - m);
      }
    }
    redA[tid] = local;
    __syncthreads();
    for (int s = STHREADS >> 1; s > 0; s >>= 1) {
      if (tid < s) redA[tid] += redA[tid + s];
      __syncthreads();
    }
    if (tid == 0) sh_Z2 = redA[0];
    __syncthreads();
  }

  // min_p: remove iff (e/Z2) < min_p * (1/Z2)
  {
    const float Z2 = sh_Z2;
    const float rhs = minp * (1.0f / Z2);
    for (int c = tid; c < CAND; c += STHREADS) {
      if (keepf[c]) {
        u32 s = (u32)(cand[c] >> 32);
        float p2 = expf(s2f(s) - m) / Z2;
        if (p2 < rhs) keepf[c] = 0;
      }
    }
  }
  __syncthreads();

  // gumbel-max (JAX categorical), first-index tie-break
  {
    const float TINY = 1.17549435082228750797e-38f;
    u64 best = 0ull;
    for (int c = lb + tid; c < cs; c += STHREADS) {
      if (!keepf[c]) continue;
      u32 s = (u32)(cand[c] >> 32);
      u32 idx = (u32)(cand[c] & 0xFFFFFFFFull);
      float x = s2f(s);
      u32 bits = threefry_bits((u32)b * (u32)V + idx);
      float f = __uint_as_float((bits >> 9) | 0x3f800000u) - 1.0f;
      float u = fmaxf(TINY, f * 1.0f + TINY);
      float g = -logf(-logf(u));
      float sc = g + x;
      u64 key = ((u64)f2s(sc) << 32) | (u64)(0xFFFFFFFFu - idx);
      if (key > best) best = key;
    }
    red64[tid] = best;
    __syncthreads();
    for (int s = STHREADS >> 1; s > 0; s >>= 1) {
      if (tid < s) { u64 o = red64[tid + s]; if (o > red64[tid]) red64[tid] = o; }
      __syncthreads();
    }
    if (tid == 0) out[b] = (int)(0xFFFFFFFFu - (u32)(red64[0] & 0xFFFFFFFFull));
  }
}

extern "C" void kernel_launch(void* const* d_in, const int* in_sizes, int n_in,
                              void* d_out, int out_size, void* d_ws, size_t ws_size,
                              hipStream_t stream) {
  const float* logits = (const float*)d_in[0];
  const float* temps  = (const float*)d_in[1];
  const float* minps  = (const float*)d_in[2];
  const float* topps  = (const float*)d_in[3];
  const int*   topks  = (const int*)d_in[4];
  const int B = in_sizes[1];
  const int V = in_sizes[0] / B;
  (void)n_in; (void)out_size; (void)ws_size;

  // scratch layout: hist [B*HBINS u32] | gcount [B u32] | gcs [B u32] | gcand [B*CAND u64]
  u32* ghist  = (u32*)d_ws;
  u32* gcount = ghist + (size_t)B * HBINS;
  u32* gcs    = gcount + B;
  u64* gcand  = (u64*)(gcs + B);   // byte offset 4*(B*HBINS+2B), 8-aligned for B mult of 2

  const int nz = B * HBINS + 2 * B;
  const int slice_len = (((V + NSLICES - 1) / NSLICES) + 3) & ~3;  // multiple of 4

  zero_kernel<<<dim3((nz + 1023) / 1024), dim3(1024), 0, stream>>>(ghist, nz);
  hist_kernel<<<dim3(B * NSLICES), dim3(HTHREADS), 0, stream>>>(logits, ghist, V, slice_len);
  collect_kernel<<<dim3(B * NSLICES), dim3(CTHREADS), 0, stream>>>(
      logits, temps, topks, ghist, gcount, gcs, gcand, V, slice_len);
  Sampler_73529840107542_kernel<<<dim3(B), dim3(STHREADS), 0, stream>>>(
      minps, topps, topks, gcs, gcand, (int*)d_out, V);
}

// Round 4
// 170.545 us; speedup vs baseline: 1.3665x; 1.1851x over previous
//
#include <hip/hip_runtime.h>
#include <stdint.h>

#define HBINS 4096
#define CAND 2048
#define NSLICES 16
#define HTHREADS 256
#define CTHREADS 256
#define STHREADS 1024

typedef unsigned int u32;
typedef unsigned long long u64;

// order-preserving float->uint map (ascending uint == ascending float)
__device__ __forceinline__ u32 f2s(float f) {
  u32 b = __float_as_uint(f);
  return b ^ ((b & 0x80000000u) ? 0xFFFFFFFFu : 0x80000000u);
}
__device__ __forceinline__ float s2f(u32 s) {
  u32 b = (s & 0x80000000u) ? (s ^ 0x80000000u) : ~s;
  return __uint_as_float(b);
}
__device__ __forceinline__ u32 rotl32(u32 x, int r) { return (x << r) | (x >> (32 - r)); }

__device__ __forceinline__ u64 shfl_xor_u64(u64 v, int mask) {
  int lo = __shfl_xor((int)(u32)v, mask, 64);
  int hi = __shfl_xor((int)(u32)(v >> 32), mask, 64);
  return ((u64)(u32)hi << 32) | (u32)lo;
}

// JAX threefry2x32, partitionable counter mode, key = jax.random.key(42) -> (0,42).
__device__ __forceinline__ u32 threefry_bits(u32 ctr) {
  const u32 ks0 = 0u, ks1 = 42u, ks2 = 0x1BD11BDAu ^ 0u ^ 42u;
  u32 x0 = ks0;
  u32 x1 = ctr + ks1;
#define TFR(r) { x0 += x1; x1 = rotl32(x1, (r)); x1 ^= x0; }
  TFR(13) TFR(15) TFR(26) TFR(6)   x0 += ks1; x1 += ks2 + 1u;
  TFR(17) TFR(29) TFR(16) TFR(24)  x0 += ks2; x1 += ks0 + 2u;
  TFR(13) TFR(15) TFR(26) TFR(6)   x0 += ks0; x1 += ks1 + 3u;
  TFR(17) TFR(29) TFR(16) TFR(24)  x0 += ks1; x1 += ks2 + 4u;
  TFR(13) TFR(15) TFR(26) TFR(6)   x0 += ks2; x1 += ks0 + 5u;
#undef TFR
  return x0 ^ x1;
}

// ---------------- zero hist scratch -------------------------------------------
__global__ __launch_bounds__(1024)
void zero_kernel(u32* __restrict__ p, int n) {
  int i = blockIdx.x * 1024 + threadIdx.x;
  if (i < n) p[i] = 0u;
}

// ---------------- per-slice raw-logit histogram (full machine) ----------------
__global__ __launch_bounds__(HTHREADS)
void hist_kernel(const float* __restrict__ logits, u32* __restrict__ ghist,
                 int V, int slice_len) {
  const int row = blockIdx.x / NSLICES;
  const int sl  = blockIdx.x % NSLICES;
  const int tid = threadIdx.x;
  __shared__ u32 h[HBINS];
  for (int i = tid; i < HBINS; i += HTHREADS) h[i] = 0u;
  __syncthreads();
  int rem = V - sl * slice_len;
  if (rem > slice_len) rem = slice_len;
  if (rem < 0) rem = 0;
  const float* src = logits + (size_t)row * (size_t)V + (size_t)sl * slice_len;
  const int n4 = rem >> 2;
  const float4* p4 = (const float4*)src;
  for (int i = tid; i < n4; i += HTHREADS) {
    float4 w = p4[i];
    atomicAdd(&h[f2s(w.x) >> 20], 1u);
    atomicAdd(&h[f2s(w.y) >> 20], 1u);
    atomicAdd(&h[f2s(w.z) >> 20], 1u);
    atomicAdd(&h[f2s(w.w) >> 20], 1u);
  }
  for (int i = (n4 << 2) + tid; i < rem; i += HTHREADS)
    atomicAdd(&h[f2s(src[i]) >> 20], 1u);
  __syncthreads();
  u32* gh = ghist + (size_t)row * HBINS;
  for (int i = tid; i < HBINS; i += HTHREADS) {
    u32 c = h[i];
    if (c) atomicAdd(&gh[i], c);   // sparse merge
  }
}

// ---------------- per-row threshold select (tiny) -----------------------------
__global__ __launch_bounds__(256)
void select_kernel(const u32* __restrict__ ghist, const int* __restrict__ topks,
                   u32* __restrict__ gthr, u32* __restrict__ gcs,
                   u32* __restrict__ gcount, int V) {
  const int row = blockIdx.x;
  const int tid = threadIdx.x;
  __shared__ u32 hist[HBINS];
  __shared__ u32 part[256];
  __shared__ u32 chunk[64];
  const u32* gh = ghist + (size_t)row * HBINS;
  for (int i = tid; i < HBINS; i += 256) hist[i] = gh[i];
  __syncthreads();
  {
    u32 s = 0;
    for (int j = 0; j < 16; ++j) s += hist[tid * 16 + j];
    part[tid] = s;
  }
  __syncthreads();
  if (tid < 64) {
    chunk[tid] = part[tid * 4] + part[tid * 4 + 1] + part[tid * 4 + 2] + part[tid * 4 + 3];
  }
  __syncthreads();
  if (tid == 0) {
    int k = topks[row];
    if (k < 1) k = 1;
    if (k > V) k = V;
    const u32 ku = (u32)k;
    u32 acc = 0;
    int cstar = 0;
    for (int c = 63; c >= 0; --c) {
      if (acc + chunk[c] >= ku) { cstar = c; break; }
      acc += chunk[c];
    }
    int pstar = cstar * 4;
    for (int p = cstar * 4 + 3; p >= cstar * 4; --p) {
      if (acc + part[p] >= ku) { pstar = p; break; }
      acc += part[p];
    }
    int bstar = pstar * 16;
    for (int bq = pstar * 16 + 15; bq >= pstar * 16; --bq) {
      acc += hist[bq];
      if (acc >= ku) { bstar = bq; break; }
    }
    gthr[row] = (u32)bstar << 20;
    gcs[row] = (acc < (u32)CAND ? acc : (u32)CAND);
    gcount[row] = 0u;
  }
}

// ---------------- per-slice collect (full machine, no hist traffic) -----------
__global__ __launch_bounds__(CTHREADS)
void collect_kernel(const float* __restrict__ logits,
                    const float* __restrict__ temps,
                    const u32* __restrict__ gthr,
                    u32* __restrict__ gcount,
                    u64* __restrict__ gcand, int V, int slice_len) {
  const int row = blockIdx.x / NSLICES;
  const int sl  = blockIdx.x % NSLICES;
  const int tid = threadIdx.x;

  __shared__ u64 stage[CAND];
  __shared__ int sh_cnt, sh_base;
  if (tid == 0) sh_cnt = 0;
  __syncthreads();

  const u32 thr = gthr[row];
  const float t = temps[row];
  int rem = V - sl * slice_len;
  if (rem > slice_len) rem = slice_len;
  if (rem < 0) rem = 0;
  const float* src = logits + (size_t)row * (size_t)V + (size_t)sl * slice_len;
  const u32 ibase = (u32)(sl * slice_len);
  const int n4 = rem >> 2;
  const float4* p4 = (const float4*)src;
  for (int i = tid; i < n4; i += CTHREADS) {
    float4 w = p4[i];
    if (f2s(w.x) >= thr) { int pos = atomicAdd(&sh_cnt, 1); if (pos < CAND) stage[pos] = ((u64)f2s(w.x / t) << 32) | (ibase + 4u * i + 0u); }
    if (f2s(w.y) >= thr) { int pos = atomicAdd(&sh_cnt, 1); if (pos < CAND) stage[pos] = ((u64)f2s(w.y / t) << 32) | (ibase + 4u * i + 1u); }
    if (f2s(w.z) >= thr) { int pos = atomicAdd(&sh_cnt, 1); if (pos < CAND) stage[pos] = ((u64)f2s(w.z / t) << 32) | (ibase + 4u * i + 2u); }
    if (f2s(w.w) >= thr) { int pos = atomicAdd(&sh_cnt, 1); if (pos < CAND) stage[pos] = ((u64)f2s(w.w / t) << 32) | (ibase + 4u * i + 3u); }
  }
  for (int i = (n4 << 2) + tid; i < rem; i += CTHREADS) {
    float l = src[i];
    if (f2s(l) >= thr) { int pos = atomicAdd(&sh_cnt, 1); if (pos < CAND) stage[pos] = ((u64)f2s(l / t) << 32) | (ibase + (u32)i); }
  }
  __syncthreads();
  int n = sh_cnt;
  if (n > CAND) n = CAND;
  if (tid == 0) sh_base = (int)atomicAdd(&gcount[row], (u32)n);
  __syncthreads();
  const int base = sh_base;
  u64* gc = gcand + (size_t)row * CAND;
  for (int i = tid; i < n; i += CTHREADS) {
    int dst = base + i;
    if (dst < CAND) gc[dst] = stage[i];
  }
}

// ---------------- per-row: hybrid reg/LDS sort + softmax chain + gumbel -------
__global__ __launch_bounds__(STHREADS)
void Sampler_73529840107542_kernel(const float* __restrict__ minps,
                                   const float* __restrict__ topps,
                                   const int* __restrict__ topks,
                                   const u32* __restrict__ gcs,
                                   const u64* __restrict__ gcand,
                                   int* __restrict__ out, int V) {
  const int b = blockIdx.x;
  const int tid = threadIdx.x;
  const int w = tid >> 6;
  const int l = tid & 63;
  const float one_minus_p = 1.0f - topps[b];
  const float minp = minps[b];
  int k = topks[b];
  if (k < 1) k = 1;
  if (k > V) k = V;

  __shared__ __align__(16) unsigned char arena[34816];
  u64* cand   = (u64*)(arena);              // [0,16384)
  float* bufA = (float*)(arena + 16384);    // [16384,24576) e / p
  float* bufB = (float*)(arena + 24576);    // [24576,32768) cumsum
  unsigned char* keepf = arena + 32768;     // [32768,34816)
  u64* red64  = (u64*)(arena + 16384);      // aliases bufA (argmax stage)
  float* redA = (float*)(arena + 16384);    // aliases bufA (Z2 stage)
  float* redB = (float*)(arena + 24576);    // aliases bufB (Z1 stage)

  __shared__ int sh_lb;
  __shared__ u32 sh_Ts;
  __shared__ float sh_m, sh_Z1, sh_Z2;

  const int cs = (int)gcs[b];
  const u64* gc = gcand + (size_t)b * CAND;
  const int e_lo = (w << 7) + l;      // wave w owns elements [w*128, w*128+128)
  const int e_hi = e_lo + 64;
  const u64 SENT = 0xFFFFFFFFFFFFFFFFull;
  u64 k0 = (e_lo < cs) ? gc[e_lo] : SENT;
  u64 k1 = (e_hi < cs) ? gc[e_hi] : SENT;

  // bitonic sort of 2048 (value,idx) keys, ascending == JAX stable argsort.
  // strides <=32: shfl_xor; stride 64: register swap; strides >=128: LDS.
  for (int size = 2; size <= CAND; size <<= 1) {
    for (int s = size >> 1; s > 0; s >>= 1) {
      if (s >= 128) {
        cand[e_lo] = k0; cand[e_hi] = k1;
        __syncthreads();
        u64 p0 = cand[e_lo ^ s], p1 = cand[e_hi ^ s];
        {
          bool keepmin = (((e_lo & s) == 0) == ((e_lo & size) == 0));
          if (keepmin ? (p0 < k0) : (p0 > k0)) k0 = p0;
        }
        {
          bool keepmin = (((e_hi & s) == 0) == ((e_hi & size) == 0));
          if (keepmin ? (p1 < k1) : (p1 > k1)) k1 = p1;
        }
        __syncthreads();
      } else if (s == 64) {
        bool asc = ((e_lo & size) == 0);   // e_hi has same direction (size>=128)
        if ((k0 > k1) == asc) { u64 t = k0; k0 = k1; k1 = t; }
      } else {
        u64 p0 = shfl_xor_u64(k0, s);
        u64 p1 = shfl_xor_u64(k1, s);
        {
          bool keepmin = (((l & s) == 0) == ((e_lo & size) == 0));
          if (keepmin ? (p0 < k0) : (p0 > k0)) k0 = p0;
        }
        {
          bool keepmin = (((l & s) == 0) == ((e_hi & size) == 0));
          if (keepmin ? (p1 < k1) : (p1 > k1)) k1 = p1;
        }
      }
    }
  }
  cand[e_lo] = k0; cand[e_hi] = k1;
  __syncthreads();

  if (tid == 0) {
    int ti = cs - k; if (ti < 0) ti = 0;
    sh_Ts = (u32)(cand[ti] >> 32);             // k-th largest x (exact)
    sh_m  = s2f((u32)(cand[cs - 1] >> 32));    // row max
  }
  __syncthreads();
  const u32 Ts = sh_Ts;
  const float m = sh_m;

  // first survivor slot (values >= Ts form a contiguous suffix of [0,cs))
  for (int c = tid; c < cs; c += STHREADS) {
    u32 s = (u32)(cand[c] >> 32);
    if (s >= Ts && (c == 0 || (u32)(cand[c - 1] >> 32) < Ts)) sh_lb = c;
  }
  __syncthreads();
  const int lb = sh_lb;

  // e = exp(x - m); exact 0 for masked / pad
  for (int c = tid; c < CAND; c += STHREADS) {
    float e = 0.0f;
    if (c < cs) {
      u32 s = (u32)(cand[c] >> 32);
      if (s >= Ts) e = expf(s2f(s) - m);
    }
    bufA[c] = e;
  }
  __syncthreads();

  // Z1 tree reduce (association identical to round 3)
  {
    float local = bufA[tid] + bufA[tid + STHREADS];
    redB[tid] = local;
    __syncthreads();
    for (int s = STHREADS >> 1; s > 0; s >>= 1) {
      if (tid < s) redB[tid] += redB[tid + s];
      __syncthreads();
    }
    if (tid == 0) sh_Z1 = redB[0];
    __syncthreads();
  }

  // p = e/Z1
  const float Z1 = sh_Z1;
  for (int c = tid; c < CAND; c += STHREADS) bufA[c] = bufA[c] / Z1;
  __syncthreads();

  // exact sequential cumsum, wave-parallelized: lane l of wave 0 computes
  // carry + v0 + ... + vl in strict left-to-right order (skipped adds are
  // exact +0.0f) -> bit-identical to a single-thread sequential cumsum.
  if (w == 0) {
    float carry = 0.0f;
    for (int base = lb; base < cs; base += 64) {
      int c = base + l;
      float v = (c < cs) ? bufA[c] : 0.0f;
      float acc = carry;
      for (int j = 0; j < 64; ++j) {
        float t = __shfl(v, j, 64);
        acc += (l >= j) ? t : 0.0f;
      }
      if (c < cs) bufB[c] = acc;
      carry = __shfl(acc, 63, 64);
    }
  }
  __syncthreads();

  // top-p keep flags: drop iff cumsum <= 1-p, never drop last sorted pos
  for (int c = tid; c < CAND; c += STHREADS) {
    unsigned char kf = 0;
    if (c < cs) {
      u32 s = (u32)(cand[c] >> 32);
      if (s >= Ts && (c == cs - 1 || bufB[c] > one_minus_p)) kf = 1;
    }
    keepf[c] = kf;
  }
  __syncthreads();

  // Z2 tree reduce (association identical to round 3)
  {
    float local = 0.0f;
    for (int c = tid; c < CAND; c += STHREADS) {
      if (keepf[c]) {
        u32 s = (u32)(cand[c] >> 32);
        local += expf(s2f(s) - m);
      }
    }
    redA[tid] = local;
    __syncthreads();
    for (int s = STHREADS >> 1; s > 0; s >>= 1) {
      if (tid < s) redA[tid] += redA[tid + s];
      __syncthreads();
    }
    if (tid == 0) sh_Z2 = redA[0];
    __syncthreads();
  }

  // min_p: remove iff (e/Z2) < min_p * (1/Z2)
  {
    const float Z2 = sh_Z2;
    const float rhs = minp * (1.0f / Z2);
    for (int c = tid; c < CAND; c += STHREADS) {
      if (keepf[c]) {
        u32 s = (u32)(cand[c] >> 32);
        float p2 = expf(s2f(s) - m) / Z2;
        if (p2 < rhs) keepf[c] = 0;
      }
    }
  }
  __syncthreads();

  // gumbel-max (JAX categorical), first-index tie-break
  {
    const float TINY = 1.17549435082228750797e-38f;
    u64 best = 0ull;
    for (int c = lb + tid; c < cs; c += STHREADS) {
      if (!keepf[c]) continue;
      u32 s = (u32)(cand[c] >> 32);
      u32 idx = (u32)(cand[c] & 0xFFFFFFFFull);
      float x = s2f(s);
      u32 bits = threefry_bits((u32)b * (u32)V + idx);
      float f = __uint_as_float((bits >> 9) | 0x3f800000u) - 1.0f;
      float u = fmaxf(TINY, f * 1.0f + TINY);
      float g = -logf(-logf(u));
      float sc = g + x;
      u64 key = ((u64)f2s(sc) << 32) | (u64)(0xFFFFFFFFu - idx);
      if (key > best) best = key;
    }
    red64[tid] = best;
    __syncthreads();
    for (int s = STHREADS >> 1; s > 0; s >>= 1) {
      if (tid < s) { u64 o = red64[tid + s]; if (o > red64[tid]) red64[tid] = o; }
      __syncthreads();
    }
    if (tid == 0) out[b] = (int)(0xFFFFFFFFu - (u32)(red64[0] & 0xFFFFFFFFull));
  }
}

extern "C" void kernel_launch(void* const* d_in, const int* in_sizes, int n_in,
                              void* d_out, int out_size, void* d_ws, size_t ws_size,
                              hipStream_t stream) {
  const float* logits = (const float*)d_in[0];
  const float* temps  = (const float*)d_in[1];
  const float* minps  = (const float*)d_in[2];
  const float* topps  = (const float*)d_in[3];
  const int*   topks  = (const int*)d_in[4];
  const int B = in_sizes[1];
  const int V = in_sizes[0] / B;
  (void)n_in; (void)out_size; (void)ws_size;

  // scratch: ghist [B*HBINS] | gcount [B] | gcs [B] | gthr [B] | gcand [B*CAND u64]
  u32* ghist  = (u32*)d_ws;
  u32* gcount = ghist + (size_t)B * HBINS;
  u32* gcs    = gcount + B;
  u32* gthr   = gcs + B;
  u64* gcand  = (u64*)(gthr + B);   // byte offset 4*B*(HBINS+3): 8-aligned for even B

  const int nz = B * HBINS;
  const int slice_len = (((V + NSLICES - 1) / NSLICES) + 3) & ~3;

  zero_kernel<<<dim3((nz + 1023) / 1024), dim3(1024), 0, stream>>>(ghist, nz);
  hist_kernel<<<dim3(B * NSLICES), dim3(HTHREADS), 0, stream>>>(logits, ghist, V, slice_len);
  select_kernel<<<dim3(B), dim3(256), 0, stream>>>(ghist, topks, gthr, gcs, gcount, V);
  collect_kernel<<<dim3(B * NSLICES), dim3(CTHREADS), 0, stream>>>(
      logits, temps, gthr, gcount, gcand, V, slice_len);
  Sampler_73529840107542_kernel<<<dim3(B), dim3(STHREADS), 0, stream>>>(
      minps, topps, topks, gcs, gcand, (int*)d_out, V);
}